// Round 13
// baseline (132.701 us; speedup 1.0000x reference)
//
#include <hip/hip_runtime.h>
#include <cstdint>
#include <cstddef>

#define FMIN_F (-3.402823466e38f)

__device__ __forceinline__ float wave_sum(float v) {
#pragma unroll
    for (int off = 32; off > 0; off >>= 1)
        v += __shfl_down(v, off, 64);
    return v; // valid in lane 0
}

__device__ __forceinline__ void load16_to_lds(const float4* g, float4* l) {
    __builtin_amdgcn_global_load_lds(
        (const __attribute__((address_space(1))) void*)g,
        (__attribute__((address_space(3))) void*)l, 16, 0, 0);
}

// ---------------- GEMV: fire-and-forget W stream via global_load_lds -------
// R12 closed the matrix: occupancy/VGPR/pattern/X-path all ruled out; every
// VGPR-destination read kernel caps at 2.4 TB/s because the <=64-VGPR
// allocator interleaves issue/drain (~2 loads in flight/wave). The one
// untried mechanism, shared by the only fast kernel in every table (fill,
// 7 TB/s @ 9.5% occ): memory ops with NO register destination. Here W is
// streamed with global_load_lds (16B, zero VGPRs), wave-private double-
// buffered 8KB tiles, NO barriers in the loop, one vmcnt(0) per tile.
// Swizzle both-sides (rule 21): source col ^= row&7 at stage, slot ^= row&7
// at read -> 2-way bank aliasing (free, m136).
// Block: (mat, 16-row chunk, 1 batch) as R12 (batch-twin L2 sharing).
// Wave: col quarter (1024 floats) of the 16 rows = 8 tiles of 16x128.
// LDS: X 16KB + 4 waves x 2 x 8KB = 80KB -> 2 blocks/CU, 8 waves/CU.
template <int NMAT>
__global__ __launch_bounds__(256) void gemv_gl_kernel(
    const float* __restrict__ X,                   // [4][4096]
    const float* __restrict__ W0, const float* __restrict__ B0,
    const float* __restrict__ W1, const float* __restrict__ B1,
    const float* __restrict__ W2, const float* __restrict__ B2,
    float scale0,
    float* __restrict__ Y)                         // [NMAT*4][4096]
{
    __shared__ float4 sX[1024];                    // 16 KB (aliased for s_part later)
    __shared__ float4 tiles[4][2][512];            // 64 KB wave-private dbuf

    const int o     = blockIdx.x;
    const int batch = (o >> 3) & 3;
    const int cm    = (o >> 5) * 8 + (o & 7);
    const int mi    = (NMAT == 1) ? 0 : (cm >> 8);
    const int chunk = cm & 255;

    const int tid = threadIdx.x;
    const float4* X4 = (const float4*)X + (size_t)batch * 1024;
    for (int i = tid; i < 1024; i += 256) sX[i] = X4[i];
    __syncthreads();

    const int wave = tid >> 6;
    const int lane = tid & 63;
    const int row  = lane & 15;                    // lane's row in tile
    const int c    = lane >> 4;                    // lane's col slot

    const float* W  = (mi == 0) ? W0 : (mi == 1) ? W1 : W2;
    const float* Bs = (mi == 0) ? B0 : (mi == 1) ? B1 : B2;
    // wave's base: chunk rows, wave's col-quarter (256 float4)
    const float4* W4 = (const float4*)W + (size_t)(chunk * 16) * 1024 + wave * 256;

    float acc = 0.f;

    // ---- stage tile t into parity buffer p (8 x 1KB segments, no VGPR) ----
    auto stage = [&](int t, int p) {
        float4* dst = &tiles[wave][p][0];
#pragma unroll
        for (int s = 0; s < 8; ++s) {
            const int i  = s * 64 + lane;          // linear LDS slot
            const int rr = i >> 5;                 // slot's row
            const int cf = (i & 31) ^ (rr & 7);    // inverse-swizzled source col
            load16_to_lds(W4 + (size_t)rr * 1024 + t * 32 + cf, dst + s * 64);
        }
    };
    // ---- consume tile in buffer p: swizzled ds_read_b128 + FMA ----
    auto consume = [&](int t, int p) {
        const float4* tb = &tiles[wave][p][0];
#pragma unroll
        for (int j = 0; j < 8; ++j) {
            const int cf   = c * 8 + j;                        // true col (f4)
            const int slot = row * 32 + (cf ^ (row & 7));      // swizzled slot
            const float4 w = tb[slot];
            const float4 x = sX[wave * 256 + t * 32 + cf];     // broadcast in phase
            acc += w.x * x.x + w.y * x.y + w.z * x.z + w.w * x.w;
        }
    };

    stage(0, 0);
    asm volatile("s_waitcnt vmcnt(0)" ::: "memory");
#pragma unroll 1
    for (int t = 0; t < 8; ++t) {
        if (t + 1 < 8) stage(t + 1, (t + 1) & 1);
        consume(t, t & 1);
        asm volatile("s_waitcnt vmcnt(0)" ::: "memory");
    }

    // reduce over col-slots (c): lanes row, row+16, row+32, row+48
    acc += __shfl_xor(acc, 16, 64);
    acc += __shfl_xor(acc, 32, 64);

    __syncthreads();                               // sX reads done -> alias it
    float* s_part = (float*)sX;                    // [4 waves][16 rows]
    if (lane < 16) s_part[wave * 16 + row] = acc;
    __syncthreads();
    if (tid < 16) {
        float s = s_part[tid] + s_part[16 + tid] + s_part[32 + tid] + s_part[48 + tid];
        const int r = chunk * 16 + tid;
        s += Bs[r];
        if (mi == 0) s *= scale0;
        Y[((size_t)(mi * 4 + batch)) * 4096 + r] = s;
    }
}

// ---------------- Attention phase 1: scores ----------------
__global__ __launch_bounds__(256) void score_kernel(
    const float* __restrict__ qkv,     // [3][4][4096]
    const float* __restrict__ pk,      // [B,H,2048,128]
    const float* __restrict__ amask,   // [B,1,1,2049]
    const float* __restrict__ cam,     // [B*H,1,2049]
    const int* __restrict__ sbp, const int* __restrict__ rbp,
    float* __restrict__ scores)        // [128][512]
{
    constexpr int PAST = 2048, S = 2049, HD = 128;
    const int bh = blockIdx.y;
    const int b  = bh >> 5;
    const int h  = bh & 31;
    const int SB = sbp[0], RB = rbp[0];
    const int NS = SB + 1;
    const int NA = NS + RB + 1;

    const int wave = threadIdx.x >> 6;
    const int lane = threadIdx.x & 63;

    const float* qh   = qkv + (size_t)b * 4096 + h * HD;
    const float* knew = qkv + (size_t)(4 + b) * 4096 + h * HD;
    const float2 ql = ((const float2*)qh)[lane];

#pragma unroll
    for (int j = 0; j < 8; ++j) {
        const int i = blockIdx.x * 32 + j * 4 + wave;
        if (i >= NA) continue;
        const int s = (i < NS) ? i : (PAST - RB + (i - NS));
        const float2* kr = (s < PAST)
            ? (const float2*)(pk + ((size_t)bh * PAST + s) * HD)
            : (const float2*)knew;
        const float2 kk = kr[lane];
        float p = ql.x * kk.x + ql.y * kk.y;
        p = wave_sum(p);
        if (lane == 0) {
            const float m  = cam[(size_t)bh * S + s];
            float sc = fmaxf(p + amask[(size_t)b * S + s], FMIN_F);
            sc = sc * m + (1.0f - m) * FMIN_F;
            scores[(size_t)bh * 512 + i] = sc;
        }
    }
}

// ---------------- Attention phase 2: softmax + coefficient fixups ----------------
__global__ __launch_bounds__(256) void softmax_kernel(
    const float* __restrict__ ps,      // [B*H,2048]
    const int* __restrict__ sbp, const int* __restrict__ rbp,
    float* __restrict__ scores)        // [128][512] in/out
{
    constexpr int PAST = 2048;
    const int bh = blockIdx.x;
    const int SB = sbp[0], RB = rbp[0];
    const int NS = SB + 1;
    const int NA = NS + RB + 1;
    const int tid = threadIdx.x;

    __shared__ float s_c[512];
    __shared__ float s_red[256];
    __shared__ float s_mm;

    for (int i = tid; i < NA; i += 256) s_c[i] = scores[(size_t)bh * 512 + i];

    {
        float part = 0.0f;
        const int cnt = SB + RB;
        for (int i = tid; i < cnt; i += 256) {
            const int idx = (i < SB) ? i : (PAST - RB + (i - SB));
            part += ps[(size_t)bh * PAST + idx];
        }
        s_red[tid] = part;
    }
    __syncthreads();
#pragma unroll
    for (int st = 128; st > 0; st >>= 1) {
        if (tid < st) s_red[tid] += s_red[tid + st];
        __syncthreads();
    }
    if (tid == 0) {
        const float mean = s_red[0] / (float)(SB + RB);
        const float prob = ps[(size_t)bh * PAST + (PAST - RB)] / mean;
        s_mm = (prob > 1.0f) ? (1.0f / 32.0f) : 0.0f;
    }
    __syncthreads();

    float mx = -INFINITY;
    for (int i = tid; i < NA; i += 256) mx = fmaxf(mx, s_c[i]);
    s_red[tid] = mx;
    __syncthreads();
#pragma unroll
    for (int st = 128; st > 0; st >>= 1) {
        if (tid < st) s_red[tid] = fmaxf(s_red[tid], s_red[tid + st]);
        __syncthreads();
    }
    const float gmax = s_red[0];
    __syncthreads();

    float lsum = 0.0f;
    for (int i = tid; i < NA; i += 256) {
        const float e = expf(s_c[i] - gmax);
        s_c[i] = e;
        lsum += e;
    }
    s_red[tid] = lsum;
    __syncthreads();
#pragma unroll
    for (int st = 128; st > 0; st >>= 1) {
        if (tid < st) s_red[tid] += s_red[tid + st];
        __syncthreads();
    }
    const float inv = 1.0f / s_red[0];
    __syncthreads();
    for (int i = tid; i < NA; i += 256) s_c[i] *= inv;
    __syncthreads();

    if (tid == 0) {
        float sm = 0.0f;
#pragma unroll
        for (int j = 1; j <= 32; ++j) sm += s_c[NS + j];
        s_c[NS] += s_mm * sm;       // folded CAM value-merge
        s_c[SB]  = 0.99f;           // pinned col * 0.99 value scale
    }
    __syncthreads();

    for (int i = tid; i < NA; i += 256) scores[(size_t)bh * 512 + i] = s_c[i];
}

// ---------------- Attention phase 3: PV partials ----------------
__global__ __launch_bounds__(256) void pv_kernel(
    const float* __restrict__ qkv,     // for v_new
    const float* __restrict__ pv,      // [B,H,2048,128]
    const float* __restrict__ coeff,   // [128][512]
    const int* __restrict__ sbp, const int* __restrict__ rbp,
    float* __restrict__ partial)       // [128][8][128]
{
    constexpr int PAST = 2048, HD = 128;
    const int bh = blockIdx.y;
    const int b  = bh >> 5;
    const int h  = bh & 31;
    const int SB = sbp[0], RB = rbp[0];
    const int NS = SB + 1;
    const int NA = NS + RB + 1;
    const int CPC = (NA + 7) >> 3;
    const int i0 = blockIdx.x * CPC;
    const int i1 = min(NA, i0 + CPC);

    const int tid  = threadIdx.x;
    const int d    = tid & 127;
    const int half = tid >> 7;

    __shared__ float s_co[64];
    __shared__ float s_red[256];

    if (tid < i1 - i0) s_co[tid] = coeff[(size_t)bh * 512 + i0 + tid];
    __syncthreads();

    const float* vnew = qkv + (size_t)(8 + b) * 4096 + h * HD;

    float acc = 0.0f;
    for (int i = i0 + half; i < i1; i += 2) {
        const int s = (i < NS) ? i : (PAST - RB + (i - NS));
        const float* vr = (s < PAST)
            ? (pv + ((size_t)bh * PAST + s) * HD)
            : vnew;
        acc += s_co[i - i0] * vr[d];
    }
    s_red[tid] = acc;
    __syncthreads();
    if (tid < 128)
        partial[((size_t)bh * 8 + blockIdx.x) * HD + d] = s_red[tid] + s_red[tid + 128];
}

// ---------------- Attention phase 4: reduce partials ----------------
__global__ __launch_bounds__(256) void attn_reduce_kernel(
    const float* __restrict__ partial,  // [128][8][128]
    float* __restrict__ attn_out)       // [4][4096] == [128][128]
{
    const int idx = blockIdx.x * 256 + threadIdx.x;
    const int bh = idx >> 7;
    const int d  = idx & 127;
    float s = 0.0f;
#pragma unroll
    for (int c = 0; c < 8; ++c)
        s += partial[(size_t)bh * 1024 + c * 128 + d];
    attn_out[idx] = s;
}

extern "C" void kernel_launch(void* const* d_in, const int* in_sizes, int n_in,
                              void* d_out, int out_size, void* d_ws, size_t ws_size,
                              hipStream_t stream)
{
    const float* hs = (const float*)d_in[0];
    const float* pk = (const float*)d_in[1];
    const float* pv = (const float*)d_in[2];
    const float* am = (const float*)d_in[3];
    const float* cm = (const float*)d_in[4];
    const float* ps = (const float*)d_in[5];
    const float* Wq = (const float*)d_in[6];
    const float* bq = (const float*)d_in[7];
    const float* Wk = (const float*)d_in[8];
    const float* bk = (const float*)d_in[9];
    const float* Wv = (const float*)d_in[10];
    const float* bv = (const float*)d_in[11];
    const float* Wo = (const float*)d_in[12];
    const float* bo = (const float*)d_in[13];
    const int*   sb = (const int*)d_in[14];
    const int*   rb = (const int*)d_in[15];

    float* qkv  = (float*)d_ws;                   // 49152
    float* aout = qkv + 3 * 4 * 4096;             // 16384
    float* sc   = aout + 4 * 4096;                // 65536
    float* part = sc + 128 * 512;                 // 131072
    float* out  = (float*)d_out;

    const float scaling = 0.08838834764831845f;   // 128^-0.5

    gemv_gl_kernel<3><<<3072, 256, 0, stream>>>(hs, Wq, bq, Wk, bk, Wv, bv, scaling, qkv);

    score_kernel<<<dim3(16, 128), 256, 0, stream>>>(qkv, pk, am, cm, sb, rb, sc);
    softmax_kernel<<<128, 256, 0, stream>>>(ps, sb, rb, sc);
    pv_kernel<<<dim3(8, 128), 256, 0, stream>>>(qkv, pv, sc, sb, rb, part);
    attn_reduce_kernel<<<64, 256, 0, stream>>>(part, aout);

    gemv_gl_kernel<1><<<1024, 256, 0, stream>>>(aout, Wo, bo, Wo, bo, Wo, bo, 1.0f, out);
}

// Round 14
// 90.260 us; speedup vs baseline: 1.4702x; 1.4702x over previous
//
#include <hip/hip_runtime.h>
#include <cstdint>
#include <cstddef>

#define FMIN_F (-3.402823466e38f)

__device__ __forceinline__ float wave_sum(float v) {
#pragma unroll
    for (int off = 32; off > 0; off >>= 1)
        v += __shfl_down(v, off, 64);
    return v; // valid in lane 0
}

// ---------------- GEMV: contiguous-walk (best measured: R9, 90.9us) --------
// Final configuration. R3-R13 matrix established a ~2.45 TB/s aggregate
// read ceiling for this context (holds at any occupancy/VGPR/pattern/
// X-path/load-destination; even fully-L3-warm replays run at the same
// rate, while fills write at 7 TB/s). 256 MB of fp32 weights must be
// re-read every launch (stateless harness) -> ~85-105us floor; this
// kernel sits on it. Block owns 16 consecutive rows (256KB) walked
// front-to-back in 4KB whole-block requests; X columns in registers
// (fixed per quarter); 2-row double buffer; block emits final biased rows.
template <int NMAT>
__global__ __launch_bounds__(256, 2) void gemv_cw_kernel(
    const float* __restrict__ X,                                  // [4][4096]
    const float* __restrict__ W0, const float* __restrict__ B0,
    const float* __restrict__ W1, const float* __restrict__ B1,
    const float* __restrict__ W2, const float* __restrict__ B2,
    float scale0,
    float* __restrict__ Y)                                        // [NMAT*4][4096]
{
    const int tid  = threadIdx.x;
    const int wave = tid >> 6;
    const int lane = tid & 63;
    const int bid  = blockIdx.x;
    const int mi      = (NMAT == 1) ? 0 : (bid >> 8);
    const int rowbase = ((NMAT == 1) ? bid : (bid & 255)) * 16;

    const float* W  = (mi == 0) ? W0 : (mi == 1) ? W1 : W2;
    const float* Bs = (mi == 0) ? B0 : (mi == 1) ? B1 : B2;
    const float4* W4 = (const float4*)W + (size_t)rowbase * 1024;
    const float4* X4 = (const float4*)X;

    // X: this thread's fixed column per quarter, all 4 batches (16 float4).
    float4 xq[4][4];                              // [quarter][batch]
#pragma unroll
    for (int q = 0; q < 4; ++q)
#pragma unroll
        for (int b = 0; b < 4; ++b)
            xq[q][b] = X4[b * 1024 + q * 256 + tid];

    __shared__ float s_part[16][4][4];            // [row][wave][batch]

    float4 wA[4], wB[4];
#pragma unroll
    for (int q = 0; q < 4; ++q) wA[q] = W4[q * 256 + tid];      // row 0

#pragma unroll 1
    for (int r2 = 0; r2 < 8; ++r2) {
        const int r0 = 2 * r2;
        // prefetch row r0+1 into wB while computing row r0 from wA
#pragma unroll
        for (int q = 0; q < 4; ++q)
            wB[q] = W4[(size_t)(r0 + 1) * 1024 + q * 256 + tid];
        {
            float a0 = 0.f, a1 = 0.f, a2 = 0.f, a3 = 0.f;
#pragma unroll
            for (int q = 0; q < 4; ++q) {
                const float4 w = wA[q];
                a0 += w.x * xq[q][0].x + w.y * xq[q][0].y + w.z * xq[q][0].z + w.w * xq[q][0].w;
                a1 += w.x * xq[q][1].x + w.y * xq[q][1].y + w.z * xq[q][1].z + w.w * xq[q][1].w;
                a2 += w.x * xq[q][2].x + w.y * xq[q][2].y + w.z * xq[q][2].z + w.w * xq[q][2].w;
                a3 += w.x * xq[q][3].x + w.y * xq[q][3].y + w.z * xq[q][3].z + w.w * xq[q][3].w;
            }
            a0 = wave_sum(a0); a1 = wave_sum(a1);
            a2 = wave_sum(a2); a3 = wave_sum(a3);
            if (lane == 0) {
                s_part[r0][wave][0] = a0; s_part[r0][wave][1] = a1;
                s_part[r0][wave][2] = a2; s_part[r0][wave][3] = a3;
            }
        }
        // prefetch row (r0+2)&15 into wA (wraps at block end; in-bounds)
#pragma unroll
        for (int q = 0; q < 4; ++q)
            wA[q] = W4[(size_t)((r0 + 2) & 15) * 1024 + q * 256 + tid];
        {
            float a0 = 0.f, a1 = 0.f, a2 = 0.f, a3 = 0.f;
#pragma unroll
            for (int q = 0; q < 4; ++q) {
                const float4 w = wB[q];
                a0 += w.x * xq[q][0].x + w.y * xq[q][0].y + w.z * xq[q][0].z + w.w * xq[q][0].w;
                a1 += w.x * xq[q][1].x + w.y * xq[q][1].y + w.z * xq[q][1].z + w.w * xq[q][1].w;
                a2 += w.x * xq[q][2].x + w.y * xq[q][2].y + w.z * xq[q][2].z + w.w * xq[q][2].w;
                a3 += w.x * xq[q][3].x + w.y * xq[q][3].y + w.z * xq[q][3].z + w.w * xq[q][3].w;
            }
            a0 = wave_sum(a0); a1 = wave_sum(a1);
            a2 = wave_sum(a2); a3 = wave_sum(a3);
            if (lane == 0) {
                s_part[r0 + 1][wave][0] = a0; s_part[r0 + 1][wave][1] = a1;
                s_part[r0 + 1][wave][2] = a2; s_part[r0 + 1][wave][3] = a3;
            }
        }
    }
    __syncthreads();
    if (tid < 64) {
        const int r = tid >> 2, b = tid & 3;
        float s = s_part[r][0][b] + s_part[r][1][b]
                + s_part[r][2][b] + s_part[r][3][b];
        s += Bs[rowbase + r];
        if (mi == 0) s *= scale0;
        Y[((size_t)(mi * 4 + b)) * 4096 + rowbase + r] = s;
    }
}

// ---------------- Attention phase 1: scores ----------------
__global__ __launch_bounds__(256) void score_kernel(
    const float* __restrict__ qkv,     // [3][4][4096]
    const float* __restrict__ pk,      // [B,H,2048,128]
    const float* __restrict__ amask,   // [B,1,1,2049]
    const float* __restrict__ cam,     // [B*H,1,2049]
    const int* __restrict__ sbp, const int* __restrict__ rbp,
    float* __restrict__ scores)        // [128][512]
{
    constexpr int PAST = 2048, S = 2049, HD = 128;
    const int bh = blockIdx.y;
    const int b  = bh >> 5;
    const int h  = bh & 31;
    const int SB = sbp[0], RB = rbp[0];
    const int NS = SB + 1;
    const int NA = NS + RB + 1;

    const int wave = threadIdx.x >> 6;
    const int lane = threadIdx.x & 63;

    const float* qh   = qkv + (size_t)b * 4096 + h * HD;
    const float* knew = qkv + (size_t)(4 + b) * 4096 + h * HD;
    const float2 ql = ((const float2*)qh)[lane];

#pragma unroll
    for (int j = 0; j < 8; ++j) {
        const int i = blockIdx.x * 32 + j * 4 + wave;
        if (i >= NA) continue;
        const int s = (i < NS) ? i : (PAST - RB + (i - NS));
        const float2* kr = (s < PAST)
            ? (const float2*)(pk + ((size_t)bh * PAST + s) * HD)
            : (const float2*)knew;
        const float2 kk = kr[lane];
        float p = ql.x * kk.x + ql.y * kk.y;
        p = wave_sum(p);
        if (lane == 0) {
            const float m  = cam[(size_t)bh * S + s];
            float sc = fmaxf(p + amask[(size_t)b * S + s], FMIN_F);
            sc = sc * m + (1.0f - m) * FMIN_F;
            scores[(size_t)bh * 512 + i] = sc;
        }
    }
}

// ---------------- Attention phase 2: softmax + coefficient fixups ----------------
__global__ __launch_bounds__(256) void softmax_kernel(
    const float* __restrict__ ps,      // [B*H,2048]
    const int* __restrict__ sbp, const int* __restrict__ rbp,
    float* __restrict__ scores)        // [128][512] in/out
{
    constexpr int PAST = 2048;
    const int bh = blockIdx.x;
    const int SB = sbp[0], RB = rbp[0];
    const int NS = SB + 1;
    const int NA = NS + RB + 1;
    const int tid = threadIdx.x;

    __shared__ float s_c[512];
    __shared__ float s_red[256];
    __shared__ float s_mm;

    for (int i = tid; i < NA; i += 256) s_c[i] = scores[(size_t)bh * 512 + i];

    {
        float part = 0.0f;
        const int cnt = SB + RB;
        for (int i = tid; i < cnt; i += 256) {
            const int idx = (i < SB) ? i : (PAST - RB + (i - SB));
            part += ps[(size_t)bh * PAST + idx];
        }
        s_red[tid] = part;
    }
    __syncthreads();
#pragma unroll
    for (int st = 128; st > 0; st >>= 1) {
        if (tid < st) s_red[tid] += s_red[tid + st];
        __syncthreads();
    }
    if (tid == 0) {
        const float mean = s_red[0] / (float)(SB + RB);
        const float prob = ps[(size_t)bh * PAST + (PAST - RB)] / mean;
        s_mm = (prob > 1.0f) ? (1.0f / 32.0f) : 0.0f;
    }
    __syncthreads();

    float mx = -INFINITY;
    for (int i = tid; i < NA; i += 256) mx = fmaxf(mx, s_c[i]);
    s_red[tid] = mx;
    __syncthreads();
#pragma unroll
    for (int st = 128; st > 0; st >>= 1) {
        if (tid < st) s_red[tid] = fmaxf(s_red[tid], s_red[tid + st]);
        __syncthreads();
    }
    const float gmax = s_red[0];
    __syncthreads();

    float lsum = 0.0f;
    for (int i = tid; i < NA; i += 256) {
        const float e = expf(s_c[i] - gmax);
        s_c[i] = e;
        lsum += e;
    }
    s_red[tid] = lsum;
    __syncthreads();
#pragma unroll
    for (int st = 128; st > 0; st >>= 1) {
        if (tid < st) s_red[tid] += s_red[tid + st];
        __syncthreads();
    }
    const float inv = 1.0f / s_red[0];
    __syncthreads();
    for (int i = tid; i < NA; i += 256) s_c[i] *= inv;
    __syncthreads();

    if (tid == 0) {
        float sm = 0.0f;
#pragma unroll
        for (int j = 1; j <= 32; ++j) sm += s_c[NS + j];
        s_c[NS] += s_mm * sm;       // folded CAM value-merge
        s_c[SB]  = 0.99f;           // pinned col * 0.99 value scale
    }
    __syncthreads();

    for (int i = tid; i < NA; i += 256) scores[(size_t)bh * 512 + i] = s_c[i];
}

// ---------------- Attention phase 3: PV partials ----------------
__global__ __launch_bounds__(256) void pv_kernel(
    const float* __restrict__ qkv,     // for v_new
    const float* __restrict__ pv,      // [B,H,2048,128]
    const float* __restrict__ coeff,   // [128][512]
    const int* __restrict__ sbp, const int* __restrict__ rbp,
    float* __restrict__ partial)       // [128][8][128]
{
    constexpr int PAST = 2048, HD = 128;
    const int bh = blockIdx.y;
    const int b  = bh >> 5;
    const int h  = bh & 31;
    const int SB = sbp[0], RB = rbp[0];
    const int NS = SB + 1;
    const int NA = NS + RB + 1;
    const int CPC = (NA + 7) >> 3;
    const int i0 = blockIdx.x * CPC;
    const int i1 = min(NA, i0 + CPC);

    const int tid  = threadIdx.x;
    const int d    = tid & 127;
    const int half = tid >> 7;

    __shared__ float s_co[64];
    __shared__ float s_red[256];

    if (tid < i1 - i0) s_co[tid] = coeff[(size_t)bh * 512 + i0 + tid];
    __syncthreads();

    const float* vnew = qkv + (size_t)(8 + b) * 4096 + h * HD;

    float acc = 0.0f;
    for (int i = i0 + half; i < i1; i += 2) {
        const int s = (i < NS) ? i : (PAST - RB + (i - NS));
        const float* vr = (s < PAST)
            ? (pv + ((size_t)bh * PAST + s) * HD)
            : vnew;
        acc += s_co[i - i0] * vr[d];
    }
    s_red[tid] = acc;
    __syncthreads();
    if (tid < 128)
        partial[((size_t)bh * 8 + blockIdx.x) * HD + d] = s_red[tid] + s_red[tid + 128];
}

// ---------------- Attention phase 4: reduce partials ----------------
__global__ __launch_bounds__(256) void attn_reduce_kernel(
    const float* __restrict__ partial,  // [128][8][128]
    float* __restrict__ attn_out)       // [4][4096] == [128][128]
{
    const int idx = blockIdx.x * 256 + threadIdx.x;
    const int bh = idx >> 7;
    const int d  = idx & 127;
    float s = 0.0f;
#pragma unroll
    for (int c = 0; c < 8; ++c)
        s += partial[(size_t)bh * 1024 + c * 128 + d];
    attn_out[idx] = s;
}

extern "C" void kernel_launch(void* const* d_in, const int* in_sizes, int n_in,
                              void* d_out, int out_size, void* d_ws, size_t ws_size,
                              hipStream_t stream)
{
    const float* hs = (const float*)d_in[0];
    const float* pk = (const float*)d_in[1];
    const float* pv = (const float*)d_in[2];
    const float* am = (const float*)d_in[3];
    const float* cm = (const float*)d_in[4];
    const float* ps = (const float*)d_in[5];
    const float* Wq = (const float*)d_in[6];
    const float* bq = (const float*)d_in[7];
    const float* Wk = (const float*)d_in[8];
    const float* bk = (const float*)d_in[9];
    const float* Wv = (const float*)d_in[10];
    const float* bv = (const float*)d_in[11];
    const float* Wo = (const float*)d_in[12];
    const float* bo = (const float*)d_in[13];
    const int*   sb = (const int*)d_in[14];
    const int*   rb = (const int*)d_in[15];

    float* qkv  = (float*)d_ws;                 // 3*4*4096 = 49152
    float* aout = qkv + 3 * 4 * 4096;           // 16384
    float* sc   = aout + 4 * 4096;              // 65536
    float* part = sc + 128 * 512;               // 131072
    float* out  = (float*)d_out;

    const float scaling = 0.08838834764831845f;  // 128^-0.5

    gemv_cw_kernel<3><<<768, 256, 0, stream>>>(hs, Wq, bq, Wk, bk, Wv, bv, scaling, qkv);
    score_kernel<<<dim3(16, 128), 256, 0, stream>>>(qkv, pk, am, cm, sb, rb, sc);
    softmax_kernel<<<128, 256, 0, stream>>>(ps, sb, rb, sc);
    pv_kernel<<<dim3(8, 128), 256, 0, stream>>>(qkv, pv, sc, sb, rb, part);
    attn_reduce_kernel<<<64, 256, 0, stream>>>(part, aout);
    gemv_cw_kernel<1><<<256, 256, 0, stream>>>(aout, Wo, bo, Wo, bo, Wo, bo, 1.0f, out);
}